// Round 2
// baseline (116.815 us; speedup 1.0000x reference)
//
#include <hip/hip_runtime.h>
#include <math.h>

#define B_    16384
#define C_    256
#define N_    128
#define M_    20
#define S_    3
#define EMIT_ 26

// One WAVE (64 lanes) per batch row. No LDS, no __syncthreads.
// Lane decomposition for the FC phase: lane = jg*16 + ic
//   ic = lane & 15  -> owns c[16*ic .. 16*ic+15]
//   jg = lane >> 4  -> owns j-group {0..6},{7..13},{14..19},{20..25}
__global__ __launch_bounds__(256) void ntm_wave_kernel(
    const float* __restrict__ ctrl,    // (B, C)
    const float* __restrict__ w_prev,  // (B, N)
    const float* __restrict__ Mt,      // (B, N, M)
    const float* __restrict__ W,       // (C, EMIT)
    const float* __restrict__ bvec,    // (EMIT)
    float* __restrict__ out)           // (B, N)
{
    const int lane = threadIdx.x & 63;
    const int wid  = threadIdx.x >> 6;
    const int b    = blockIdx.x * 4 + wid;

    const int ic = lane & 15;
    const int jg = lane >> 4;
    const int jbase = (jg == 0) ? 0 : (jg == 1) ? 7 : (jg == 2) ? 14 : 20;

    // ---- load this lane's 16-float chunk of the controller row ----
    const float* crow = ctrl + (size_t)b * C_;
    float c[16];
    #pragma unroll
    for (int u = 0; u < 4; ++u) {
        float4 v = *(const float4*)(crow + ic * 16 + u * 4);
        c[u*4+0] = v.x; c[u*4+1] = v.y; c[u*4+2] = v.z; c[u*4+3] = v.w;
    }

    // ---- FC partials: acc[r] = sum_{i in chunk} c[i] * W[i][jbase+r] ----
    float acc[7] = {0.f,0.f,0.f,0.f,0.f,0.f,0.f};
    #pragma unroll
    for (int io = 0; io < 16; ++io) {
        const float cv = c[io];
        const float* Wp = W + (size_t)(ic * 16 + io) * EMIT_;
        #pragma unroll
        for (int r = 0; r < 7; ++r) {
            int j = jbase + r; if (j > 25) j = 25;   // jg3 r=6 is a dummy
            acc[r] = fmaf(cv, Wp[j], acc[r]);
        }
    }

    // ---- reduce over the 16 lanes sharing jg, add bias, tanh ----
    #pragma unroll
    for (int r = 0; r < 7; ++r) {
        float a = acc[r];
        a += __shfl_xor(a, 1);
        a += __shfl_xor(a, 2);
        a += __shfl_xor(a, 4);
        a += __shfl_xor(a, 8);
        int j = jbase + r; if (j > 25) j = 25;
        acc[r] = tanhf(a + bvec[j]);
    }

    // ---- broadcast all 26 fc values to every lane (register-resident) ----
    float fc[EMIT_];
    #pragma unroll
    for (int j = 0; j < EMIT_; ++j) {
        const int g = (j < 7) ? 0 : (j < 14) ? 1 : (j < 20) ? 2 : 3;
        const int r = j - ((g == 0) ? 0 : (g == 1) ? 7 : (g == 2) ? 14 : 20);
        fc[j] = __shfl(acc[r], g << 4);
    }

    // ---- head parameters ----
    float ksq = 0.f;
    #pragma unroll
    for (int m = 0; m < M_; ++m) ksq = fmaf(fc[m], fc[m], ksq);

    const float beta  = log1pf(__expf(fc[20]));          // softplus (|arg|<1)
    const float g     = 1.f / (1.f + __expf(-fc[21]));   // sigmoid
    const float e0 = __expf(fc[22]);
    const float e1 = __expf(fc[23]);
    const float e2 = __expf(fc[24]);
    const float einv = 1.f / (e0 + e1 + e2);
    const float s0 = e0 * einv, s1 = e1 * einv, s2 = e2 * einv;
    const float gamma = 1.f + log1pf(__expf(fc[25]));

    // ---- cosine similarity logits for n = lane and n = lane+64 ----
    const float* M0 = Mt + ((size_t)b * N_ + lane) * M_;
    const float* M1 = M0 + (size_t)64 * M_;
    float dot0 = 0.f, msq0 = 0.f, dot1 = 0.f, msq1 = 0.f;
    #pragma unroll
    for (int i = 0; i < 5; ++i) {
        float4 v = *(const float4*)(M0 + 4 * i);
        dot0 = fmaf(fc[4*i+0], v.x, dot0);  msq0 = fmaf(v.x, v.x, msq0);
        dot0 = fmaf(fc[4*i+1], v.y, dot0);  msq0 = fmaf(v.y, v.y, msq0);
        dot0 = fmaf(fc[4*i+2], v.z, dot0);  msq0 = fmaf(v.z, v.z, msq0);
        dot0 = fmaf(fc[4*i+3], v.w, dot0);  msq0 = fmaf(v.w, v.w, msq0);
    }
    #pragma unroll
    for (int i = 0; i < 5; ++i) {
        float4 v = *(const float4*)(M1 + 4 * i);
        dot1 = fmaf(fc[4*i+0], v.x, dot1);  msq1 = fmaf(v.x, v.x, msq1);
        dot1 = fmaf(fc[4*i+1], v.y, dot1);  msq1 = fmaf(v.y, v.y, msq1);
        dot1 = fmaf(fc[4*i+2], v.z, dot1);  msq1 = fmaf(v.z, v.z, msq1);
        dot1 = fmaf(fc[4*i+3], v.w, dot1);  msq1 = fmaf(v.w, v.w, msq1);
    }
    const float l0 = beta * dot0 / sqrtf(ksq * msq0);
    const float l1 = beta * dot1 / sqrtf(ksq * msq1);

    // ---- softmax over the 128 logits (2 per lane, wave butterfly) ----
    float mx = fmaxf(l0, l1);
    #pragma unroll
    for (int o = 32; o; o >>= 1) mx = fmaxf(mx, __shfl_xor(mx, o));
    const float p0 = __expf(l0 - mx);
    const float p1 = __expf(l1 - mx);
    float sm = p0 + p1;
    #pragma unroll
    for (int o = 32; o; o >>= 1) sm += __shfl_xor(sm, o);
    const float inv_sm = 1.f / sm;

    // ---- interpolate with previous weights ----
    const float* wp = w_prev + (size_t)b * N_;
    const float A = g * (p0 * inv_sm) + (1.f - g) * wp[lane];       // wg[lane]
    const float Bv = g * (p1 * inv_sm) + (1.f - g) * wp[lane + 64]; // wg[lane+64]

    // ---- circular shift: wt[n] = wg[n+1]*s0 + wg[n]*s1 + wg[n-1]*s2 ----
    const float Ap  = __shfl(A,  (lane + 1) & 63);
    const float Bp  = __shfl(Bv, (lane + 1) & 63);
    const float Am  = __shfl(A,  (lane + 63) & 63);
    const float Bm  = __shfl(Bv, (lane + 63) & 63);
    const float A0  = __shfl(A, 0);
    const float A63 = __shfl(A, 63);
    const float B0  = __shfl(Bv, 0);
    const float B63 = __shfl(Bv, 63);

    const float np0 = (lane == 63) ? B0  : Ap;   // wg[(lane+1)   % 128]
    const float nm0 = (lane == 0)  ? B63 : Am;   // wg[(lane-1)   % 128]
    const float np1 = (lane == 63) ? A0  : Bp;   // wg[(lane+65)  % 128]
    const float nm1 = (lane == 0)  ? A63 : Bm;   // wg[(lane+63)  % 128]

    const float wt0 = np0 * s0 + A  * s1 + nm0 * s2;
    const float wt1 = np1 * s0 + Bv * s1 + nm1 * s2;

    // ---- sharpen + normalize ----
    const float wr0 = (wt0 > 0.f) ? __expf(gamma * __logf(wt0)) : 0.f;
    const float wr1 = (wt1 > 0.f) ? __expf(gamma * __logf(wt1)) : 0.f;
    float tot = wr0 + wr1;
    #pragma unroll
    for (int o = 32; o; o >>= 1) tot += __shfl_xor(tot, o);
    const float inv_tot = 1.f / tot;

    float* orow = out + (size_t)b * N_;
    orow[lane]      = wr0 * inv_tot;
    orow[lane + 64] = wr1 * inv_tot;
}

extern "C" void kernel_launch(void* const* d_in, const int* in_sizes, int n_in,
                              void* d_out, int out_size, void* d_ws, size_t ws_size,
                              hipStream_t stream) {
    const float* ctrl   = (const float*)d_in[0];
    const float* w_prev = (const float*)d_in[1];
    const float* Mt     = (const float*)d_in[2];
    const float* W      = (const float*)d_in[3];
    const float* bvec   = (const float*)d_in[4];
    float* out = (float*)d_out;

    ntm_wave_kernel<<<dim3(B_ / 4), dim3(256), 0, stream>>>(ctrl, w_prev, Mt, W, bvec, out);
}

// Round 3
// 42.799 us; speedup vs baseline: 2.7294x; 2.7294x over previous
//
#include <hip/hip_runtime.h>
#include <math.h>

#define B_    16384
#define C_    256
#define N_    128
#define M_    20
#define S_    3
#define EMIT_ 26

// One WAVE (64 lanes) per batch row; 4 independent waves per 256-thread block.
// No __syncthreads anywhere. FC decomposition: j = lane&31 (clamped to 25),
// q = lane>>5 sums half the C dimension; W loads are j-consecutive (coalesced
// L1 runs), c comes from same-wave LDS (broadcast + free 2-way conflict).
// M_t rows and w_prev are prefetched into registers BEFORE the FC phase so
// their HBM latency hides under FC compute.
__global__ __launch_bounds__(256, 4) void ntm_wave2_kernel(
    const float* __restrict__ ctrl,    // (B, C)
    const float* __restrict__ w_prev,  // (B, N)
    const float* __restrict__ Mt,      // (B, N, M)
    const float* __restrict__ W,       // (C, EMIT)
    const float* __restrict__ bvec,    // (EMIT)
    float* __restrict__ out)           // (B, N)
{
    const int lane = threadIdx.x & 63;
    const int wid  = threadIdx.x >> 6;
    const int b    = blockIdx.x * 4 + wid;

    __shared__ float c_lds[4][C_];

    // ---- prefetch: M rows (n=lane, n=lane+64) and w_prev, independent of FC ----
    const float* M0 = Mt + ((size_t)b * N_ + lane) * M_;
    const float* M1 = M0 + (size_t)64 * M_;
    float4 ma[5], mb[5];
    #pragma unroll
    for (int i = 0; i < 5; ++i) ma[i] = *(const float4*)(M0 + 4 * i);
    #pragma unroll
    for (int i = 0; i < 5; ++i) mb[i] = *(const float4*)(M1 + 4 * i);
    const float wp0 = w_prev[(size_t)b * N_ + lane];
    const float wp1 = w_prev[(size_t)b * N_ + lane + 64];

    // ---- stage controller row into this wave's LDS region (coalesced) ----
    const float* crow = ctrl + (size_t)b * C_;
    {
        float4 cv = *(const float4*)(crow + lane * 4);
        *(float4*)&c_lds[wid][lane * 4] = cv;
    }
    // same-wave RAW on LDS: compiler inserts lgkmcnt wait; no barrier needed.

    // ---- FC: fc = tanh(c @ W + b) ----
    const int jr = lane & 31;
    const int j  = (jr < EMIT_) ? jr : (EMIT_ - 1);   // lanes 26..31 duplicate j=25
    const int q  = lane >> 5;
    const float* cq = &c_lds[wid][q * 128];
    const float* Wq = W + (size_t)(q * 128) * EMIT_ + j;
    float a0 = 0.f, a1 = 0.f;
    #pragma unroll 8
    for (int io = 0; io < 128; io += 2) {
        a0 = fmaf(cq[io],     Wq[(size_t)io * EMIT_],       a0);
        a1 = fmaf(cq[io + 1], Wq[(size_t)(io + 1) * EMIT_], a1);
    }
    float a = a0 + a1;
    a += __shfl_xor(a, 32);              // combine the two q-halves
    a = tanhf(a + bvec[j]);              // lanes 0..25 now hold fc[j]

    float fc[EMIT_];
    #pragma unroll
    for (int jj = 0; jj < EMIT_; ++jj) fc[jj] = __shfl(a, jj);

    // ---- head parameters (computed redundantly per lane; cheap) ----
    float ksq = 0.f;
    #pragma unroll
    for (int m = 0; m < M_; ++m) ksq = fmaf(fc[m], fc[m], ksq);

    const float beta  = log1pf(__expf(fc[20]));          // softplus (|arg|<1)
    const float g     = 1.f / (1.f + __expf(-fc[21]));   // sigmoid
    const float e0 = __expf(fc[22]);
    const float e1 = __expf(fc[23]);
    const float e2 = __expf(fc[24]);
    const float einv = 1.f / (e0 + e1 + e2);
    const float s0 = e0 * einv, s1 = e1 * einv, s2 = e2 * einv;
    const float gamma = 1.f + log1pf(__expf(fc[25]));

    // ---- cosine similarity logits (M data already in registers) ----
    float dot0 = 0.f, msq0 = 0.f, dot1 = 0.f, msq1 = 0.f;
    #pragma unroll
    for (int i = 0; i < 5; ++i) {
        float4 v = ma[i];
        dot0 = fmaf(fc[4*i+0], v.x, dot0);  msq0 = fmaf(v.x, v.x, msq0);
        dot0 = fmaf(fc[4*i+1], v.y, dot0);  msq0 = fmaf(v.y, v.y, msq0);
        dot0 = fmaf(fc[4*i+2], v.z, dot0);  msq0 = fmaf(v.z, v.z, msq0);
        dot0 = fmaf(fc[4*i+3], v.w, dot0);  msq0 = fmaf(v.w, v.w, msq0);
    }
    #pragma unroll
    for (int i = 0; i < 5; ++i) {
        float4 v = mb[i];
        dot1 = fmaf(fc[4*i+0], v.x, dot1);  msq1 = fmaf(v.x, v.x, msq1);
        dot1 = fmaf(fc[4*i+1], v.y, dot1);  msq1 = fmaf(v.y, v.y, msq1);
        dot1 = fmaf(fc[4*i+2], v.z, dot1);  msq1 = fmaf(v.z, v.z, msq1);
        dot1 = fmaf(fc[4*i+3], v.w, dot1);  msq1 = fmaf(v.w, v.w, msq1);
    }
    const float l0 = beta * dot0 / sqrtf(ksq * msq0);
    const float l1 = beta * dot1 / sqrtf(ksq * msq1);

    // ---- softmax over the 128 logits (2 per lane, wave butterfly) ----
    float mx = fmaxf(l0, l1);
    #pragma unroll
    for (int o = 32; o; o >>= 1) mx = fmaxf(mx, __shfl_xor(mx, o));
    const float p0 = __expf(l0 - mx);
    const float p1 = __expf(l1 - mx);
    float sm = p0 + p1;
    #pragma unroll
    for (int o = 32; o; o >>= 1) sm += __shfl_xor(sm, o);
    const float inv_sm = 1.f / sm;

    // ---- interpolate with previous weights ----
    const float A  = g * (p0 * inv_sm) + (1.f - g) * wp0;   // wg[lane]
    const float Bv = g * (p1 * inv_sm) + (1.f - g) * wp1;   // wg[lane+64]

    // ---- circular shift: wt[n] = wg[n+1]*s0 + wg[n]*s1 + wg[n-1]*s2 ----
    const float Ap  = __shfl(A,  (lane + 1) & 63);
    const float Bp  = __shfl(Bv, (lane + 1) & 63);
    const float Am  = __shfl(A,  (lane + 63) & 63);
    const float Bm  = __shfl(Bv, (lane + 63) & 63);
    const float A0  = __shfl(A, 0);
    const float A63 = __shfl(A, 63);
    const float B0  = __shfl(Bv, 0);
    const float B63 = __shfl(Bv, 63);

    const float np0 = (lane == 63) ? B0  : Ap;   // wg[(lane+1)   % 128]
    const float nm0 = (lane == 0)  ? B63 : Am;   // wg[(lane-1)   % 128]
    const float np1 = (lane == 63) ? A0  : Bp;   // wg[(lane+65)  % 128]
    const float nm1 = (lane == 0)  ? A63 : Bm;   // wg[(lane+63)  % 128]

    const float wt0 = np0 * s0 + A  * s1 + nm0 * s2;
    const float wt1 = np1 * s0 + Bv * s1 + nm1 * s2;

    // ---- sharpen + normalize ----
    const float wr0 = (wt0 > 0.f) ? __expf(gamma * __logf(wt0)) : 0.f;
    const float wr1 = (wt1 > 0.f) ? __expf(gamma * __logf(wt1)) : 0.f;
    float tot = wr0 + wr1;
    #pragma unroll
    for (int o = 32; o; o >>= 1) tot += __shfl_xor(tot, o);
    const float inv_tot = 1.f / tot;

    float* orow = out + (size_t)b * N_;
    orow[lane]      = wr0 * inv_tot;
    orow[lane + 64] = wr1 * inv_tot;
}

extern "C" void kernel_launch(void* const* d_in, const int* in_sizes, int n_in,
                              void* d_out, int out_size, void* d_ws, size_t ws_size,
                              hipStream_t stream) {
    const float* ctrl   = (const float*)d_in[0];
    const float* w_prev = (const float*)d_in[1];
    const float* Mt     = (const float*)d_in[2];
    const float* W      = (const float*)d_in[3];
    const float* bvec   = (const float*)d_in[4];
    float* out = (float*)d_out;

    ntm_wave2_kernel<<<dim3(B_ / 4), dim3(256), 0, stream>>>(ctrl, w_prev, Mt, W, bvec, out);
}